// Round 13
// baseline (610.228 us; speedup 1.0000x reference)
//
#include <hip/hip_runtime.h>

#define NN   100000
#define NE   1600000
#define DIM  128
#define ZB    391                 // zero-deg blocks (ceil NN/256)
#define CASTB 6250                // cast blocks (2 float4/thread)
#define CWB   384                 // castw blocks (3*128*256/256)
#define EB    6250                // edge blocks (NE/256 exact)
#define NTILES (NN / 16)          // 6250 node-tiles of 16 rows
#define LB    ((NTILES + 15) / 16)   // 391 k_lin blocks (16 tiles each)
#define GB    (NN / 4)            // 25000 gather blocks

// Ledger: dense gather (1 node/wave, 4 slots x 16 chunks, 2 chains) = 58us
// structural ceiling (~7TB/s L2 random-line service).  Fusion arc falsified
// (R9 96us barrier-coupled / R11 121us atomic chain-head).  R12 banked 417.9
// (split + EPB4096).  R13: replace deterministic 2-pass binning (hist/scanrow/
// bin2/build, 6.4MB binned round-trip x3) with atomic-scatter CSR: degcnt ->
// self-sufficient scan (meta+cursor) -> scatter.  Within-node csr order becomes
// non-deterministic -- numerically ~1e-6 (f32 accum), absmax expected to move
// slightly off 0.01757812.  k_lin: 1024-thr blocks (staging 50->25MB) +
// B-prefetch before the staging barrier (value-exact).

typedef short          s16x8 __attribute__((ext_vector_type(8)));
typedef unsigned short u16x8 __attribute__((ext_vector_type(8)));
typedef float          f32x4 __attribute__((ext_vector_type(4)));

__device__ __forceinline__ unsigned short f2b(float f) {
    unsigned u = __float_as_uint(f);
    unsigned r = ((u >> 16) & 1u) + 0x7FFFu;   // RNE
    return (unsigned short)((u + r) >> 16);
}
__device__ __forceinline__ float b2f(unsigned short h) {
    return __uint_as_float(((unsigned)h) << 16);
}

// ---- fused prep: [0,ZB) zero deg | [ZB,ZB+CASTB) cast_x x2 | rest castw ----
__global__ void k_prep(const float* __restrict__ x, unsigned short* __restrict__ xb,
                       int* __restrict__ deg,
                       const float* __restrict__ W1l, const float* __restrict__ W1r,
                       const float* __restrict__ W2l, const float* __restrict__ W2r,
                       const float* __restrict__ W3l, const float* __restrict__ W3r,
                       unsigned short* __restrict__ Wt1, unsigned short* __restrict__ Wt2,
                       unsigned short* __restrict__ Wt3) {
    int t = threadIdx.x, b = blockIdx.x;
    if (b < ZB) {
        int n = b * 256 + t;
        if (n < NN) deg[n] = 0;
    } else if (b < ZB + CASTB) {
        // fp32 -> bf16 feature cast, 2 float4 per thread (independent loads)
        int i0 = (b - ZB) * 512 + t;
        float4 v0 = ((const float4*)x)[i0];
        float4 v1 = ((const float4*)x)[i0 + 256];
        ushort4 o0, o1;
        o0.x = f2b(v0.x); o0.y = f2b(v0.y); o0.z = f2b(v0.z); o0.w = f2b(v0.w);
        o1.x = f2b(v1.x); o1.y = f2b(v1.y); o1.z = f2b(v1.z); o1.w = f2b(v1.w);
        ((ushort4*)xb)[i0]       = o0;
        ((ushort4*)xb)[i0 + 256] = o1;
    } else {
        // weight cast: Wt[n][k] = bf16( k<128 ? Wl[k][n] : Wr[k-128][n] )
        int i = (b - ZB - CASTB) * 256 + t;   // 3 * 128 * 256
        int L = i >> 15;
        int rem = i & 32767;
        int n = rem >> 8;
        int k = rem & 255;
        const float* Wl = (L == 0) ? W1l : (L == 1) ? W2l : W3l;
        const float* Wr = (L == 0) ? W1r : (L == 1) ? W2r : W3r;
        unsigned short* Wt = (L == 0) ? Wt1 : (L == 1) ? Wt2 : Wt3;
        float v = (k < 128) ? Wl[k * 128 + n] : Wr[(k - 128) * 128 + n];
        Wt[n * 256 + k] = f2b(v);
    }
}

// ---- degree count: 1.6M atomics over 100K addresses (~16/addr, low conflict)
__global__ void k_degcnt(const int* __restrict__ dst, int* __restrict__ deg) {
    int i = blockIdx.x * 256 + threadIdx.x;   // NE % 256 == 0, grid exact
    atomicAdd(&deg[dst[i]], 1);
}

// ---- meta build: self-sufficient prefix (each block sums deg[0..start) from
// L2, ~78MB aggregate) + 256-elem LDS scan -> meta{rs,d,1/d} + cursor=rs.
__global__ void k_meta(const int* __restrict__ deg, int4* __restrict__ meta,
                       int* __restrict__ cursor) {
    __shared__ int ps[256];
    int t = threadIdx.x, b = blockIdx.x;
    int start = b * 256;
    int partial = 0;
    for (int i = t; i < start; i += 256) partial += deg[i];
    ps[t] = partial;
    __syncthreads();
    for (int off = 128; off > 0; off >>= 1) {
        if (t < off) ps[t] += ps[t + off];
        __syncthreads();
    }
    int S = ps[0];
    __syncthreads();
    int n = start + t;
    int d = (n < NN) ? deg[n] : 0;
    ps[t] = d;
    __syncthreads();
    for (int off = 1; off < 256; off <<= 1) {
        int a = (t >= off) ? ps[t - off] : 0;
        __syncthreads();
        ps[t] += a;
        __syncthreads();
    }
    int rs = S + (ps[t] - d);              // exclusive prefix
    if (n < NN) {
        float di = (d > 0) ? 1.0f / (float)d : 0.0f;
        int4 M; M.x = rs; M.y = d; M.z = __float_as_int(di); M.w = 0;
        meta[n]   = M;
        cursor[n] = rs;
    }
}

// ---- CSR scatter: pos = cursor[dst]++; csr[pos] = src.  Within-node order
// non-deterministic (f32 sum reorder ~1e-6 rel -- tolerated).
__global__ void k_scatter(const int* __restrict__ src, const int* __restrict__ dst,
                          int* __restrict__ cursor, int* __restrict__ csr) {
    int i = blockIdx.x * 256 + threadIdx.x;   // grid exact
    int s  = src[i];
    int d_ = dst[i];
    int pos = atomicAdd(&cursor[d_], 1);
    csr[pos] = s;
}

// ---- mean aggregation: one wave per node; 4 neighbor slots x 16 col-chunks ----
// 2 independent load+accumulate chains per lane (proven optimum); int4 meta =
// single 16B load at the chain head.  BYTE-IDENTICAL to R12 (58us, FETCH 178MB).
__global__ void k_gather(const unsigned short* __restrict__ feat,
                         const int4* __restrict__ meta,
                         const int* __restrict__ csr,
                         unsigned short* __restrict__ mean) {
    int lane = threadIdx.x & 63;
    int wv   = threadIdx.x >> 6;
    int n    = blockIdx.x * 4 + wv;        // NN % 4 == 0, grid exact
    int q = lane >> 4, c = lane & 15;      // q: neighbor slot, c: 16B column chunk
    int4 M = meta[n];
    int base = M.x;
    int d    = M.y;
    float s  = __int_as_float(M.z);
    float acc0[8], acc1[8];
#pragma unroll
    for (int t = 0; t < 8; t++) { acc0[t] = 0.0f; acc1[t] = 0.0f; }
    const u16x8* fp = (const u16x8*)feat;
    int j = q;
    for (; j + 4 < d; j += 8) {
        int s0 = csr[base + j];
        int s1 = csr[base + j + 4];
        u16x8 v0 = fp[s0 * 16 + c];
        u16x8 v1 = fp[s1 * 16 + c];
#pragma unroll
        for (int t = 0; t < 8; t++) { acc0[t] += b2f(v0[t]); acc1[t] += b2f(v1[t]); }
    }
    if (j < d) {
        int s0 = csr[base + j];
        u16x8 v0 = fp[s0 * 16 + c];
#pragma unroll
        for (int t = 0; t < 8; t++) acc0[t] += b2f(v0[t]);
    }
#pragma unroll
    for (int t = 0; t < 8; t++) acc0[t] += acc1[t];
#pragma unroll
    for (int t = 0; t < 8; t++) {
        acc0[t] += __shfl_xor(acc0[t], 16, 64);
        acc0[t] += __shfl_xor(acc0[t], 32, 64);
    }
    if (q == 0) {
        u16x8 o;
#pragma unroll
        for (int t = 0; t < 8; t++) o[t] = f2b(acc0[t] * s);
        ((u16x8*)mean)[n * 16 + c] = o;
    }
}

// ---- fused linear v4: 1024-thr blocks (16 tiles), B-prefetch before barrier.
// acc = mfma(W_frag, X_frag): col(lane&15)=node, row(quad*4+r)=outdim.
// Weight staging halved vs 512-thr (391 x 64KB = 25MB).  Value-exact vs v3.
// MODE 0: relu, bf16 output; MODE 1: no act, fp32 output
template <int MODE>
__global__ void __launch_bounds__(1024)
k_lin(const unsigned short* __restrict__ meanb,
      const unsigned short* __restrict__ hb,
      const unsigned short* __restrict__ Wt,
      const float* __restrict__ bias, void* __restrict__ out) {
    __shared__ s16x8 sW[4096];             // 64 KB
    int t = threadIdx.x;
    int lane = t & 63;
    int wv   = t >> 6;                     // 0..15
    int tile = blockIdx.x * 16 + wv;       // node tile (16 nodes)
    bool act = (tile < NTILES);
    int n0 = tile * 16;
    int q = lane >> 4, c = lane & 15;
    int row = n0 + c;
    // B-prefetch: issue global loads BEFORE weight staging (latency overlap)
    s16x8 B[8];
    if (act) {
        const s16x8* mp = (const s16x8*)meanb;
        const s16x8* hp = (const s16x8*)hb;
#pragma unroll
        for (int kt = 0; kt < 4; kt++) B[kt] = mp[row * 16 + kt * 4 + q];
#pragma unroll
        for (int kt = 0; kt < 4; kt++) B[4 + kt] = hp[row * 16 + kt * 4 + q];
    }
    // stage weights in fragment order: chunk ci -> frag (ci>>6), lane (ci&63)
    const s16x8* wp = (const s16x8*)Wt;
#pragma unroll
    for (int it = 0; it < 4; it++) {
        int ci = it * 1024 + t;
        int frag = ci >> 6, ln = ci & 63;
        int mt = frag >> 3, kt = frag & 7;
        int m = mt * 16 + (ln & 15);
        int kc = kt * 4 + (ln >> 4);
        sW[ci] = wp[m * 32 + kc];
    }
    __syncthreads();
    if (!act) return;

    const f32x4* bp = (const f32x4*)bias;
#pragma unroll
    for (int mt = 0; mt < 8; mt++) {
        f32x4 acc = {0.f, 0.f, 0.f, 0.f};
#pragma unroll
        for (int kt = 0; kt < 8; kt++)
            acc = __builtin_amdgcn_mfma_f32_16x16x32_bf16(sW[(mt * 8 + kt) * 64 + lane],
                                                          B[kt], acc, 0, 0, 0);
        f32x4 bv = bp[mt * 4 + q];         // outdims mt*16+q*4 .. +3
        int node = n0 + c;
        if (MODE == 0) {
            ushort4 o;
            float v0 = acc[0] + bv[0]; if (v0 < 0.f) v0 = 0.f;
            float v1 = acc[1] + bv[1]; if (v1 < 0.f) v1 = 0.f;
            float v2 = acc[2] + bv[2]; if (v2 < 0.f) v2 = 0.f;
            float v3 = acc[3] + bv[3]; if (v3 < 0.f) v3 = 0.f;
            o.x = f2b(v0); o.y = f2b(v1); o.z = f2b(v2); o.w = f2b(v3);
            ((ushort4*)out)[node * 32 + mt * 4 + q] = o;
        } else {
            f32x4 v;
#pragma unroll
            for (int r = 0; r < 4; r++) v[r] = acc[r] + bv[r];
            ((f32x4*)out)[node * 32 + mt * 4 + q] = v;
        }
    }
}

extern "C" void kernel_launch(void* const* d_in, const int* in_sizes, int n_in,
                              void* d_out, int out_size, void* d_ws, size_t ws_size,
                              hipStream_t stream) {
    const float* x   = (const float*)d_in[1];
    const int*   ei  = (const int*)d_in[2];
    const int*   src = ei;
    const int*   dst = ei + NE;
    const float* W1l = (const float*)d_in[3];
    const float* W1r = (const float*)d_in[4];
    const float* b1  = (const float*)d_in[5];
    const float* W2l = (const float*)d_in[6];
    const float* W2r = (const float*)d_in[7];
    const float* b2  = (const float*)d_in[8];
    const float* W3l = (const float*)d_in[9];
    const float* W3r = (const float*)d_in[10];
    const float* b3  = (const float*)d_in[11];

    // workspace carve (all 256B aligned)
    char* w = (char*)d_ws;
    auto carve = [&](size_t bytes) {
        void* p = (void*)w;
        w += (bytes + 255) & ~(size_t)255;
        return p;
    };
    int4*  meta    = (int4*)carve((size_t)NN * 16);
    int*   deg     = (int*)carve((size_t)NN * 4);
    int*   cursor  = (int*)carve((size_t)NN * 4);
    int*   csr     = (int*)carve((size_t)NE * 4);
    unsigned short* Wt1 = (unsigned short*)carve(128 * 256 * 2);
    unsigned short* Wt2 = (unsigned short*)carve(128 * 256 * 2);
    unsigned short* Wt3 = (unsigned short*)carve(128 * 256 * 2);
    unsigned short* xb    = (unsigned short*)carve((size_t)NN * DIM * 2);
    unsigned short* meanb = (unsigned short*)carve((size_t)NN * DIM * 2);
    unsigned short* h1b   = (unsigned short*)carve((size_t)NN * DIM * 2);
    unsigned short* h2b   = xb;          // x dead after layer-2 B-load

    k_prep<<<ZB + CASTB + CWB, 256, 0, stream>>>(x, xb, deg,
                                                 W1l, W1r, W2l, W2r, W3l, W3r,
                                                 Wt1, Wt2, Wt3);
    k_degcnt<<<EB, 256, 0, stream>>>(dst, deg);
    k_meta<<<ZB, 256, 0, stream>>>(deg, meta, cursor);
    k_scatter<<<EB, 256, 0, stream>>>(src, dst, cursor, csr);

    // layer 1: mean over xb -> h1 = relu(lin)
    k_gather<<<GB, 256, 0, stream>>>(xb, meta, csr, meanb);
    k_lin<0><<<LB, 1024, 0, stream>>>(meanb, xb, Wt1, b1, (void*)h1b);
    // layer 2: mean over h1 -> h2 = relu(lin)
    k_gather<<<GB, 256, 0, stream>>>(h1b, meta, csr, meanb);
    k_lin<0><<<LB, 1024, 0, stream>>>(meanb, h1b, Wt2, b2, (void*)h2b);
    // layer 3: mean over h2 -> dx_dt (fp32, no activation)
    k_gather<<<GB, 256, 0, stream>>>(h2b, meta, csr, meanb);
    k_lin<1><<<LB, 1024, 0, stream>>>(meanb, h2b, Wt3, b3, d_out);
}